// Round 1
// baseline (217.460 us; speedup 1.0000x reference)
//
#include <hip/hip_runtime.h>
#include <cstdint>
#include <cstddef>

#define TOPK 9
#define NCLS 80
#define EPSF 1e-9f

// -------- helpers --------
__device__ __forceinline__ float iou_f(float4 b1, float4 b2) {
    float x1 = fmaxf(b1.x, b2.x), y1 = fmaxf(b1.y, b2.y);
    float x2 = fminf(b1.z, b2.z), y2 = fminf(b1.w, b2.w);
    float ov = fmaxf(x2 - x1, 0.f) * fmaxf(y2 - y1, 0.f);
    float a1 = fmaxf(b1.z - b1.x, 0.f) * fmaxf(b1.w - b1.y, 0.f);
    float a2 = fmaxf(b2.z - b2.x, 0.f) * fmaxf(b2.w - b2.y, 0.f);
    return ov / (a1 + a2 - ov + EPSF);
}

// insert v into sorted-ascending key[0..TOPK-1] (static indexing only)
__device__ __forceinline__ void topk_insert(unsigned long long key[TOPK],
                                            unsigned long long v) {
    if (v < key[TOPK - 1]) {
        key[TOPK - 1] = v;
#pragma unroll
        for (int k = TOPK - 1; k > 0; --k) {
            if (key[k] < key[k - 1]) {
                unsigned long long t = key[k];
                key[k] = key[k - 1];
                key[k - 1] = t;
            }
        }
    }
}

// -------- kernel Z: zero the positive-mask --------
__global__ __launch_bounds__(256) void zero_mask_kernel(unsigned long long* p, int n) {
    int t = blockIdx.x * blockDim.x + threadIdx.x;
    if (t < n) p[t] = 0ull;
}

// -------- kernel A: per-(b,m) top-9 per level + threshold + inside check --------
// one wave (64 threads) per (b,m)
__global__ __launch_bounds__(64) void atss_topk_kernel(
    const float* __restrict__ anchors,     // [A,4]
    const float* __restrict__ gt_bboxes,   // [B,M,4]
    const float* __restrict__ pad_mask,    // [B,M]
    unsigned long long* __restrict__ pos_mask, // [B,A]
    int M, int A) {
    const int bm = blockIdx.x;
    const int b = bm / M;
    const int m = bm - b * M;
    const int lane = threadIdx.x;

    const float4 g = ((const float4*)gt_bboxes)[bm];
    const float gcx = (g.x + g.z) * 0.5f;
    const float gcy = (g.y + g.w) * 0.5f;

    __shared__ unsigned idx27[32];
    __shared__ float    iou27[32];

    const int starts[4] = {0, 6400, 8000, 8400};

    for (int lvl = 0; lvl < 3; ++lvl) {
        const int s = starts[lvl], e = starts[lvl + 1];
        unsigned long long key[TOPK];
#pragma unroll
        for (int k = 0; k < TOPK; ++k) key[k] = ~0ull;

        for (int i = s + lane; i < e; i += 64) {
            float4 a = ((const float4*)anchors)[i];
            float dx = (a.x + a.z) * 0.5f - gcx;
            float dy = (a.y + a.w) * 0.5f - gcy;
            float d = sqrtf(dx * dx + dy * dy);
            // dist >= 0: float bits preserve order; low 32 bits = idx for
            // lower-index-wins tie-break (matches jax.lax.top_k stability)
            unsigned long long kk =
                ((unsigned long long)__float_as_uint(d) << 32) | (unsigned)i;
            topk_insert(key, kk);
        }

        // butterfly allreduce: merged top-9 of all 64 lanes
#pragma unroll
        for (int st = 1; st < 64; st <<= 1) {
            unsigned long long other[TOPK];
#pragma unroll
            for (int k = 0; k < TOPK; ++k)
                other[k] = __shfl_xor(key[k], st, 64);
#pragma unroll
            for (int j = 0; j < TOPK; ++j) topk_insert(key, other[j]);
        }

        if (lane == 0) {
#pragma unroll
            for (int k = 0; k < TOPK; ++k)
                idx27[lvl * TOPK + k] = (unsigned)(key[k] & 0xFFFFFFFFu);
        }
        __syncthreads();
    }

    // IoU(gt, anchor) for the 27 candidates
    if (lane < 27) {
        float4 a = ((const float4*)anchors)[idx27[lane]];
        iou27[lane] = iou_f(g, a);
    }
    __syncthreads();

    // thr_v = mean + std(ddof=1) over the 27 candidate ious
    float sum = 0.f;
    for (int k = 0; k < 27; ++k) sum += iou27[k];
    float mean = sum * (1.0f / 27.0f);
    float var = 0.f;
    for (int k = 0; k < 27; ++k) {
        float d = iou27[k] - mean;
        var += d * d;
    }
    float thr = mean + sqrtf(var * (1.0f / 26.0f));

    float pad = pad_mask[bm];
    if (lane < 27 && pad != 0.f) {
        if (iou27[lane] > thr) {   // strict >, matches jnp.where(cand > thr_v, ...)
            unsigned ai = idx27[lane];
            float4 a = ((const float4*)anchors)[ai];
            float acx = (a.x + a.z) * 0.5f;
            float acy = (a.y + a.w) * 0.5f;
            float lt = fminf(fminf(acx - g.x, acy - g.y),
                             fminf(g.z - acx, g.w - acy));
            if (lt > EPSF) {   // strict >, matches _check_inside
                atomicOr(&pos_mask[(size_t)b * A + ai], 1ull << m);
            }
        }
    }
}

// -------- kernel B: per-(b,a) assignment --------
__global__ __launch_bounds__(256) void atss_assign_kernel(
    const float* __restrict__ anchors,    // [A,4]
    const int*   __restrict__ gt_labels,  // [B,M]
    const float* __restrict__ gt_bboxes,  // [B,M,4]
    const float* __restrict__ pred,       // [B,A,4]
    const int*   __restrict__ bg_ptr,
    const unsigned long long* __restrict__ pos_mask, // [B,A]
    float* __restrict__ out_labels,       // [B,A]
    float* __restrict__ out_bboxes,       // [B,A,4]
    float* __restrict__ piou_ws,          // [B,A]
    int M, int A, int BA) {
    int t = blockIdx.x * blockDim.x + threadIdx.x;
    if (t >= BA) return;
    int b = t / A;
    int a = t - b * A;

    unsigned long long mask = pos_mask[t];
    int mps = __popcll(mask);

    int gt = 0;
    if (mps == 1) {
        gt = __builtin_ctzll(mask);
    } else if (mps > 1) {
        // column replaced by one_hot(argmax_m ious[b,:,a]); strict > keeps
        // the first max like jnp.argmax
        float4 an = ((const float4*)anchors)[a];
        float best = -1.f;
        for (int mm = 0; mm < M; ++mm) {
            float v = iou_f(((const float4*)gt_bboxes)[b * M + mm], an);
            if (v > best) { best = v; gt = mm; }
        }
    }
    // mps==0: argmax of all-zero mask == 0 -> bbox = gt_bboxes[b,0], label = bg

    float4 gbox = ((const float4*)gt_bboxes)[b * M + gt];
    int label = (mps > 0) ? gt_labels[b * M + gt] : bg_ptr[0];

    out_labels[t] = (float)label;
    ((float4*)out_bboxes)[t] = gbox;

    float pi = 0.f;
    if (mps > 0) {
        float4 p = ((const float4*)pred)[t];
        pi = iou_f(gbox, p);   // pious.max over m == iou with assigned gt
    }
    piou_ws[t] = pi;
}

// -------- kernel C: score fill (one-hot * piou), float4-coalesced --------
__global__ __launch_bounds__(256) void atss_scores_kernel(
    const float* __restrict__ out_labels, // [B,A] (float-encoded int)
    const float* __restrict__ piou_ws,    // [B,A]
    float* __restrict__ scores,           // [B,A,80]
    int total4) {
    int t = blockIdx.x * blockDim.x + threadIdx.x;
    if (t >= total4) return;
    int anchor = t / (NCLS / 4);          // 20 float4 per anchor
    int c0 = (t - anchor * (NCLS / 4)) * 4;
    int label = (int)out_labels[anchor];  // bg=80 matches no c in [0,80)
    float pi = piou_ws[anchor];
    float4 v;
    v.x = (c0 + 0 == label) ? pi : 0.f;
    v.y = (c0 + 1 == label) ? pi : 0.f;
    v.z = (c0 + 2 == label) ? pi : 0.f;
    v.w = (c0 + 3 == label) ? pi : 0.f;
    ((float4*)scores)[t] = v;
}

extern "C" void kernel_launch(void* const* d_in, const int* in_sizes, int n_in,
                              void* d_out, int out_size, void* d_ws, size_t ws_size,
                              hipStream_t stream) {
    const float* anchors   = (const float*)d_in[0];
    const int*   gt_labels = (const int*)d_in[1];
    const float* gt_bboxes = (const float*)d_in[2];
    const float* pad_mask  = (const float*)d_in[3];
    const float* pred      = (const float*)d_in[4];
    const int*   bg_ptr    = (const int*)d_in[5];

    const int A  = in_sizes[0] / 4;   // 8400
    const int BM = in_sizes[1];       // 2048
    const int M  = 64;
    const int B  = BM / M;            // 32
    const int BA = B * A;             // 268800

    float* out_labels = (float*)d_out;
    float* out_bboxes = out_labels + (size_t)BA;
    float* scores     = out_bboxes + (size_t)BA * 4;

    unsigned long long* pos_mask = (unsigned long long*)d_ws;
    float* piou_ws = (float*)((char*)d_ws + (size_t)BA * sizeof(unsigned long long));

    zero_mask_kernel<<<(BA + 255) / 256, 256, 0, stream>>>(pos_mask, BA);
    atss_topk_kernel<<<BM, 64, 0, stream>>>(anchors, gt_bboxes, pad_mask,
                                            pos_mask, M, A);
    atss_assign_kernel<<<(BA + 255) / 256, 256, 0, stream>>>(
        anchors, gt_labels, gt_bboxes, pred, bg_ptr, pos_mask,
        out_labels, out_bboxes, piou_ws, M, A, BA);
    const int total4 = BA * (NCLS / 4);
    atss_scores_kernel<<<(total4 + 255) / 256, 256, 0, stream>>>(
        out_labels, piou_ws, scores, total4);
}

// Round 2
// 144.719 us; speedup vs baseline: 1.5026x; 1.5026x over previous
//
#include <hip/hip_runtime.h>
#include <cstdint>
#include <cstddef>

#define TOPK 9
#define NCLS 80
#define EPSF 1e-9f

// -------- helpers --------
__device__ __forceinline__ float iou_f(float4 b1, float4 b2) {
    float x1 = fmaxf(b1.x, b2.x), y1 = fmaxf(b1.y, b2.y);
    float x2 = fminf(b1.z, b2.z), y2 = fminf(b1.w, b2.w);
    float ov = fmaxf(x2 - x1, 0.f) * fmaxf(y2 - y1, 0.f);
    float a1 = fmaxf(b1.z - b1.x, 0.f) * fmaxf(b1.w - b1.y, 0.f);
    float a2 = fmaxf(b2.z - b2.x, 0.f) * fmaxf(b2.w - b2.y, 0.f);
    return ov / (a1 + a2 - ov + EPSF);
}

// -------- kernel Z: zero the positive-mask --------
__global__ __launch_bounds__(256) void zero_mask_kernel(unsigned long long* p, int n) {
    int t = blockIdx.x * blockDim.x + threadIdx.x;
    if (t < n) p[t] = 0ull;
}

// -------- kernel A: per-(b,m) top-9 per level + threshold + inside check ------
// One wave per (b,m). Anchor centers form a regular grid per level, so the
// top-9 nearest (incl. all tie-competitors at the 9th distance) provably lie
// inside an 8x8 index window around the gt center (disk r=2.5s always holds
// >=9 lattice points; window covers Chebyshev +-3s). 64 candidates = 1/lane.
// Packed key (dist_bits<<32 | global_idx) reproduces jax.lax.top_k exact
// ordering + lowest-index tie-break, identical to the round-1 full scan.
__global__ __launch_bounds__(64) void atss_topk_kernel(
    const float* __restrict__ anchors,     // [A,4]
    const float* __restrict__ gt_bboxes,   // [B,M,4]
    const float* __restrict__ pad_mask,    // [B,M]
    unsigned long long* __restrict__ pos_mask, // [B,A]
    int M, int A) {
    const int bm = blockIdx.x;
    const int b = bm / M;
    const int m = bm - b * M;
    const int lane = threadIdx.x;

    const float4 g = ((const float4*)gt_bboxes)[bm];
    const float gcx = (g.x + g.z) * 0.5f;
    const float gcy = (g.y + g.w) * 0.5f;

    __shared__ unsigned idx27[32];
    __shared__ float    iou27[32];

    const int fsL[3]  = {80, 40, 20};
    const int strL[3] = {8, 16, 32};
    const int stL[3]  = {0, 6400, 8000};

    const int wx = lane & 7;     // window col
    const int wy = lane >> 3;    // window row

    for (int lvl = 0; lvl < 3; ++lvl) {
        const int fs = fsL[lvl];
        const float s = (float)strL[lvl];
        const int st = stL[lvl];

        // nearest-below grid index: centers at (i+0.5)*s
        int fx = (int)floorf(gcx / s - 0.5f);
        int fy = (int)floorf(gcy / s - 0.5f);
        int ix0 = min(max(fx - 3, 0), fs - 8);
        int iy0 = min(max(fy - 3, 0), fs - 8);

        int gi = st + (iy0 + wy) * fs + (ix0 + wx);
        float4 a = ((const float4*)anchors)[gi];
        float ddx = (a.x + a.z) * 0.5f - gcx;
        float ddy = (a.y + a.w) * 0.5f - gcy;
        float d = sqrtf(ddx * ddx + ddy * ddy);
        unsigned long long v =
            ((unsigned long long)__float_as_uint(d) << 32) | (unsigned)gi;

        // 9 rounds of 64-lane min-allreduce; keys are unique (idx in low bits)
#pragma unroll
        for (int r = 0; r < TOPK; ++r) {
            unsigned long long mn = v;
#pragma unroll
            for (int sft = 32; sft >= 1; sft >>= 1) {
                unsigned long long o = __shfl_xor(mn, sft, 64);
                mn = (o < mn) ? o : mn;
            }
            if (lane == 0) idx27[lvl * TOPK + r] = (unsigned)mn;  // low32 = gi
            if (v == mn) v = ~0ull;
        }
    }
    __syncthreads();

    // IoU(gt, anchor) for the 27 candidates
    if (lane < 27) {
        float4 a = ((const float4*)anchors)[idx27[lane]];
        iou27[lane] = iou_f(g, a);
    }
    __syncthreads();

    // thr_v = mean + std(ddof=1) over the 27 candidate ious
    // (serial order kept identical to round 1 — passed with absmax 0)
    float sum = 0.f;
    for (int k = 0; k < 27; ++k) sum += iou27[k];
    float mean = sum * (1.0f / 27.0f);
    float var = 0.f;
    for (int k = 0; k < 27; ++k) {
        float d = iou27[k] - mean;
        var += d * d;
    }
    float thr = mean + sqrtf(var * (1.0f / 26.0f));

    float pad = pad_mask[bm];
    if (lane < 27 && pad != 0.f) {
        if (iou27[lane] > thr) {   // strict >, matches jnp.where(cand > thr_v)
            unsigned ai = idx27[lane];
            float4 a = ((const float4*)anchors)[ai];
            float acx = (a.x + a.z) * 0.5f;
            float acy = (a.y + a.w) * 0.5f;
            float lt = fminf(fminf(acx - g.x, acy - g.y),
                             fminf(g.z - acx, g.w - acy));
            if (lt > EPSF) {   // strict >, matches _check_inside
                atomicOr(&pos_mask[(size_t)b * A + ai], 1ull << m);
            }
        }
    }
}

// -------- kernel B: per-(b,a) assignment --------
__global__ __launch_bounds__(256) void atss_assign_kernel(
    const float* __restrict__ anchors,    // [A,4]
    const int*   __restrict__ gt_labels,  // [B,M]
    const float* __restrict__ gt_bboxes,  // [B,M,4]
    const float* __restrict__ pred,       // [B,A,4]
    const int*   __restrict__ bg_ptr,
    const unsigned long long* __restrict__ pos_mask, // [B,A]
    float* __restrict__ out_labels,       // [B,A]
    float* __restrict__ out_bboxes,       // [B,A,4]
    float* __restrict__ piou_ws,          // [B,A]
    int M, int A, int BA) {
    int t = blockIdx.x * blockDim.x + threadIdx.x;
    if (t >= BA) return;
    int b = t / A;
    int a = t - b * A;

    unsigned long long mask = pos_mask[t];
    int mps = __popcll(mask);

    int gt = 0;
    if (mps == 1) {
        gt = __builtin_ctzll(mask);
    } else if (mps > 1) {
        // column replaced by one_hot(argmax_m ious[b,:,a]); strict > keeps
        // the first max like jnp.argmax
        float4 an = ((const float4*)anchors)[a];
        float best = -1.f;
        for (int mm = 0; mm < M; ++mm) {
            float v = iou_f(((const float4*)gt_bboxes)[b * M + mm], an);
            if (v > best) { best = v; gt = mm; }
        }
    }
    // mps==0: argmax of all-zero mask == 0 -> bbox = gt_bboxes[b,0], label = bg

    float4 gbox = ((const float4*)gt_bboxes)[b * M + gt];
    int label = (mps > 0) ? gt_labels[b * M + gt] : bg_ptr[0];

    out_labels[t] = (float)label;
    ((float4*)out_bboxes)[t] = gbox;

    float pi = 0.f;
    if (mps > 0) {
        float4 p = ((const float4*)pred)[t];
        pi = iou_f(gbox, p);   // pious.max over m == iou with assigned gt
    }
    piou_ws[t] = pi;
}

// -------- kernel C: score fill (one-hot * piou), float4-coalesced --------
__global__ __launch_bounds__(256) void atss_scores_kernel(
    const float* __restrict__ out_labels, // [B,A] (float-encoded int)
    const float* __restrict__ piou_ws,    // [B,A]
    float* __restrict__ scores,           // [B,A,80]
    int total4) {
    int t = blockIdx.x * blockDim.x + threadIdx.x;
    if (t >= total4) return;
    int anchor = t / (NCLS / 4);          // 20 float4 per anchor
    int c0 = (t - anchor * (NCLS / 4)) * 4;
    int label = (int)out_labels[anchor];  // bg=80 matches no c in [0,80)
    float pi = piou_ws[anchor];
    float4 v;
    v.x = (c0 + 0 == label) ? pi : 0.f;
    v.y = (c0 + 1 == label) ? pi : 0.f;
    v.z = (c0 + 2 == label) ? pi : 0.f;
    v.w = (c0 + 3 == label) ? pi : 0.f;
    ((float4*)scores)[t] = v;
}

extern "C" void kernel_launch(void* const* d_in, const int* in_sizes, int n_in,
                              void* d_out, int out_size, void* d_ws, size_t ws_size,
                              hipStream_t stream) {
    const float* anchors   = (const float*)d_in[0];
    const int*   gt_labels = (const int*)d_in[1];
    const float* gt_bboxes = (const float*)d_in[2];
    const float* pad_mask  = (const float*)d_in[3];
    const float* pred      = (const float*)d_in[4];
    const int*   bg_ptr    = (const int*)d_in[5];

    const int A  = in_sizes[0] / 4;   // 8400
    const int BM = in_sizes[1];       // 2048
    const int M  = 64;
    const int B  = BM / M;            // 32
    const int BA = B * A;             // 268800

    float* out_labels = (float*)d_out;
    float* out_bboxes = out_labels + (size_t)BA;
    float* scores     = out_bboxes + (size_t)BA * 4;

    unsigned long long* pos_mask = (unsigned long long*)d_ws;
    float* piou_ws = (float*)((char*)d_ws + (size_t)BA * sizeof(unsigned long long));

    zero_mask_kernel<<<(BA + 255) / 256, 256, 0, stream>>>(pos_mask, BA);
    atss_topk_kernel<<<BM, 64, 0, stream>>>(anchors, gt_bboxes, pad_mask,
                                            pos_mask, M, A);
    atss_assign_kernel<<<(BA + 255) / 256, 256, 0, stream>>>(
        anchors, gt_labels, gt_bboxes, pred, bg_ptr, pos_mask,
        out_labels, out_bboxes, piou_ws, M, A, BA);
    const int total4 = BA * (NCLS / 4);
    atss_scores_kernel<<<(total4 + 255) / 256, 256, 0, stream>>>(
        out_labels, piou_ws, scores, total4);
}

// Round 3
// 144.548 us; speedup vs baseline: 1.5044x; 1.0012x over previous
//
#include <hip/hip_runtime.h>
#include <cstdint>
#include <cstddef>

#define TOPK 9
#define NCLS 80
#define EPSF 1e-9f

typedef float f4v __attribute__((ext_vector_type(4)));

// -------- helpers --------
__device__ __forceinline__ float iou_f(float4 b1, float4 b2) {
    float x1 = fmaxf(b1.x, b2.x), y1 = fmaxf(b1.y, b2.y);
    float x2 = fminf(b1.z, b2.z), y2 = fminf(b1.w, b2.w);
    float ov = fmaxf(x2 - x1, 0.f) * fmaxf(y2 - y1, 0.f);
    float a1 = fmaxf(b1.z - b1.x, 0.f) * fmaxf(b1.w - b1.y, 0.f);
    float a2 = fmaxf(b2.z - b2.x, 0.f) * fmaxf(b2.w - b2.y, 0.f);
    return ov / (a1 + a2 - ov + EPSF);
}

// -------- kernel Z: zero the positive-mask --------
__global__ __launch_bounds__(256) void zero_mask_kernel(unsigned long long* p, int n) {
    int t = blockIdx.x * blockDim.x + threadIdx.x;
    if (t < n) p[t] = 0ull;
}

// -------- kernel A: per-(b,m) top-9 per level + threshold + inside check ------
// One block (3 waves) per (b,m); wave w handles pyramid level w.
// Anchor centers form a regular grid per level, so the top-9 nearest (incl.
// all tie-competitors at the 9th distance) provably lie inside an 8x8 index
// window around the gt center (disk r=2.5s holds >=9 lattice points; window
// covers Chebyshev +-3s). 64 candidates = 1/lane.
// Selection by RANK: keys (dist_bits<<32 | idx) are unique; rank = #{keys <
// mine} via 64 independent broadcast shuffles (pipelined, no dependent
// chain). rank<9 lanes scatter in ascending-key order — identical output to
// the round-2 extract-min (passed absmax 0), which itself matched the full
// jax.lax.top_k scan.
__global__ __launch_bounds__(192) void atss_topk_kernel(
    const float* __restrict__ anchors,     // [A,4]
    const float* __restrict__ gt_bboxes,   // [B,M,4]
    const float* __restrict__ pad_mask,    // [B,M]
    unsigned long long* __restrict__ pos_mask, // [B,A]
    int M, int A) {
    const int bm = blockIdx.x;
    const int b = bm / M;
    const int m = bm - b * M;
    const int lane = threadIdx.x & 63;
    const int w = threadIdx.x >> 6;      // level = wave id (0..2)

    const float4 g = ((const float4*)gt_bboxes)[bm];
    const float gcx = (g.x + g.z) * 0.5f;
    const float gcy = (g.y + g.w) * 0.5f;

    __shared__ unsigned idx27[32];
    __shared__ float    iou27[32];

    const int fsL[3]  = {80, 40, 20};
    const int strL[3] = {8, 16, 32};
    const int stL[3]  = {0, 6400, 8000};

    const int fs = fsL[w];
    const float s = (float)strL[w];
    const int st = stL[w];

    // nearest-below grid index: centers at (i+0.5)*s
    int fx = (int)floorf(gcx / s - 0.5f);
    int fy = (int)floorf(gcy / s - 0.5f);
    int ix0 = min(max(fx - 3, 0), fs - 8);
    int iy0 = min(max(fy - 3, 0), fs - 8);

    const int wx = lane & 7;     // window col
    const int wy = lane >> 3;    // window row
    int gi = st + (iy0 + wy) * fs + (ix0 + wx);
    float4 a = ((const float4*)anchors)[gi];
    float ddx = (a.x + a.z) * 0.5f - gcx;
    float ddy = (a.y + a.w) * 0.5f - gcy;
    float d = sqrtf(ddx * ddx + ddy * ddy);
    unsigned long long key =
        ((unsigned long long)__float_as_uint(d) << 32) | (unsigned)gi;

    // rank via 64 independent broadcast shuffles (pipelines through LDS unit)
    int rank = 0;
#pragma unroll
    for (int j = 0; j < 64; ++j) {
        unsigned long long o = __shfl(key, j, 64);
        rank += (o < key) ? 1 : 0;
    }
    if (rank < TOPK)
        idx27[w * TOPK + rank] = (unsigned)(key & 0xFFFFFFFFu);
    __syncthreads();

    // IoU(gt, anchor) for the 27 candidates
    if (threadIdx.x < 27) {
        float4 ca = ((const float4*)anchors)[idx27[threadIdx.x]];
        iou27[threadIdx.x] = iou_f(g, ca);
    }
    __syncthreads();

    if (threadIdx.x < 27) {
        // thr_v = mean + std(ddof=1); serial order identical to rounds 1-2
        float sum = 0.f;
        for (int k = 0; k < 27; ++k) sum += iou27[k];
        float mean = sum * (1.0f / 27.0f);
        float var = 0.f;
        for (int k = 0; k < 27; ++k) {
            float dd = iou27[k] - mean;
            var += dd * dd;
        }
        float thr = mean + sqrtf(var * (1.0f / 26.0f));

        float pad = pad_mask[bm];
        if (pad != 0.f && iou27[threadIdx.x] > thr) {  // strict >, matches ref
            unsigned ai = idx27[threadIdx.x];
            float4 ca = ((const float4*)anchors)[ai];
            float acx = (ca.x + ca.z) * 0.5f;
            float acy = (ca.y + ca.w) * 0.5f;
            float lt = fminf(fminf(acx - g.x, acy - g.y),
                             fminf(g.z - acx, g.w - acy));
            if (lt > EPSF) {   // strict >, matches _check_inside
                atomicOr(&pos_mask[(size_t)b * A + ai], 1ull << m);
            }
        }
    }
}

// -------- kernel B: per-(b,a) assignment --------
__global__ __launch_bounds__(256) void atss_assign_kernel(
    const float* __restrict__ anchors,    // [A,4]
    const int*   __restrict__ gt_labels,  // [B,M]
    const float* __restrict__ gt_bboxes,  // [B,M,4]
    const float* __restrict__ pred,       // [B,A,4]
    const int*   __restrict__ bg_ptr,
    const unsigned long long* __restrict__ pos_mask, // [B,A]
    float* __restrict__ out_labels,       // [B,A]
    float* __restrict__ out_bboxes,       // [B,A,4]
    float* __restrict__ piou_ws,          // [B,A]
    int M, int A, int BA) {
    int t = blockIdx.x * blockDim.x + threadIdx.x;
    if (t >= BA) return;
    int b = t / A;
    int a = t - b * A;

    unsigned long long mask = pos_mask[t];
    int mps = __popcll(mask);

    int gt = 0;
    if (mps == 1) {
        gt = __builtin_ctzll(mask);
    } else if (mps > 1) {
        // column replaced by one_hot(argmax_m ious[b,:,a]); strict > keeps
        // the first max like jnp.argmax
        float4 an = ((const float4*)anchors)[a];
        float best = -1.f;
        for (int mm = 0; mm < M; ++mm) {
            float v = iou_f(((const float4*)gt_bboxes)[b * M + mm], an);
            if (v > best) { best = v; gt = mm; }
        }
    }
    // mps==0: argmax of all-zero mask == 0 -> bbox = gt_bboxes[b,0], label = bg

    float4 gbox = ((const float4*)gt_bboxes)[b * M + gt];
    int label = (mps > 0) ? gt_labels[b * M + gt] : bg_ptr[0];

    out_labels[t] = (float)label;
    ((float4*)out_bboxes)[t] = gbox;

    float pi = 0.f;
    if (mps > 0) {
        float4 p = ((const float4*)pred)[t];
        pi = iou_f(gbox, p);   // pious.max over m == iou with assigned gt
    }
    piou_ws[t] = pi;
}

// -------- kernel C: score fill (one-hot * piou), float4-coalesced, NT stores --
__global__ __launch_bounds__(256) void atss_scores_kernel(
    const float* __restrict__ out_labels, // [B,A] (float-encoded int)
    const float* __restrict__ piou_ws,    // [B,A]
    float* __restrict__ scores,           // [B,A,80]
    int total4) {
    int t = blockIdx.x * blockDim.x + threadIdx.x;
    if (t >= total4) return;
    int anchor = t / (NCLS / 4);          // 20 float4 per anchor
    int c0 = (t - anchor * (NCLS / 4)) * 4;
    int label = (int)out_labels[anchor];  // bg=80 matches no c in [0,80)
    float pi = piou_ws[anchor];
    f4v v;
    v.x = (c0 + 0 == label) ? pi : 0.f;
    v.y = (c0 + 1 == label) ? pi : 0.f;
    v.z = (c0 + 2 == label) ? pi : 0.f;
    v.w = (c0 + 3 == label) ? pi : 0.f;
    __builtin_nontemporal_store(v, (f4v*)scores + t);
}

extern "C" void kernel_launch(void* const* d_in, const int* in_sizes, int n_in,
                              void* d_out, int out_size, void* d_ws, size_t ws_size,
                              hipStream_t stream) {
    const float* anchors   = (const float*)d_in[0];
    const int*   gt_labels = (const int*)d_in[1];
    const float* gt_bboxes = (const float*)d_in[2];
    const float* pad_mask  = (const float*)d_in[3];
    const float* pred      = (const float*)d_in[4];
    const int*   bg_ptr    = (const int*)d_in[5];

    const int A  = in_sizes[0] / 4;   // 8400
    const int BM = in_sizes[1];       // 2048
    const int M  = 64;
    const int B  = BM / M;            // 32
    const int BA = B * A;             // 268800

    float* out_labels = (float*)d_out;
    float* out_bboxes = out_labels + (size_t)BA;
    float* scores     = out_bboxes + (size_t)BA * 4;

    unsigned long long* pos_mask = (unsigned long long*)d_ws;
    float* piou_ws = (float*)((char*)d_ws + (size_t)BA * sizeof(unsigned long long));

    zero_mask_kernel<<<(BA + 255) / 256, 256, 0, stream>>>(pos_mask, BA);
    atss_topk_kernel<<<BM, 192, 0, stream>>>(anchors, gt_bboxes, pad_mask,
                                             pos_mask, M, A);
    atss_assign_kernel<<<(BA + 255) / 256, 256, 0, stream>>>(
        anchors, gt_labels, gt_bboxes, pred, bg_ptr, pos_mask,
        out_labels, out_bboxes, piou_ws, M, A, BA);
    const int total4 = BA * (NCLS / 4);
    atss_scores_kernel<<<(total4 + 255) / 256, 256, 0, stream>>>(
        out_labels, piou_ws, scores, total4);
}